// Round 1
// baseline (368.543 us; speedup 1.0000x reference)
//
#include <hip/hip_runtime.h>
#include <math.h>

// GraphVampNet EGNN forward. B=512, N=128, K=16, H=16, NC=6, NL=4.
// One block per frame; h/x/pA/pB in LDS across all 4 layers; fixed ring
// adjacency j=(i+d)%N d=1..16 -> pure gather, cnt==16.
// e1 factored: pA[i]=h_i@W[0:16]+b+W[33], pB[j]=h_j@W[16:32].
// R5: per-layer weights in LDS; weight-base offsets LAUNDERED via empty
// asm inside the edge-group loop so LICM/CSE cannot hoist the ~576
// loop-invariant weight loads into registers (R4: hoist -> 256 VGPR +
// 398 MB scratch spill). G=2 edge pairing: each ds_read_b128 weight row
// feeds 32 FMAs. No pointer-param helpers (R2/R3 lesson: they kill SROA).
// R6: occupancy push. Grid is pinned at 512 blocks (2/CU), so waves/SIMD
// was 2 -> latency-bound (per-SIMD VALU ~15% despite 55% "any" VALUBusy).
// Now 512 threads/block (8 waves), 4 edges/thread (2 G=2 passes),
// __launch_bounds__(512,4) caps VGPR at 128 so 2 blocks/CU = 4 waves/SIMD.
// LDS kept <=80KB by having quarter-0 threads keep edge partials in regs
// across the barrier (they ARE the phase-C threads): part is [384][20].
// Phase A uses all 512 threads (8-output halves of pA/pB per thread).

#define NB   512
#define NN   128
#define HH   16
#define NCLS 6
#define NLAY 4
#define PAD  20   // LDS row stride (dwords); rows 80B -> 16B-aligned

// LDS weight-buffer float offsets (all multiples of 4 -> 16B aligned)
#define W_E1   0      // 544 = 34*16
#define W_E1B  544    // 16
#define W_E2   560    // 256
#define W_E2B  816    // 16
#define W_C1   832    // 256
#define W_C1B  1088   // 16
#define W_C2   1104   // 16
#define W_N1   1120   // 512
#define W_N1B  1632   // 16
#define W_N2   1648   // 256
#define W_N2B  1904   // 16
#define W_TOT  1920

__device__ __forceinline__ float silu_f(float v) {
    return __fdividef(v, 1.f + __expf(-v));
}

extern "C" __global__ __launch_bounds__(512, 4)
void GraphVampNet_73624329388105_kernel(
    const float* __restrict__ data,
    const float* __restrict__ emb_w,
    const float* __restrict__ ein_w, const float* __restrict__ ein_b,
    const float* __restrict__ eout_w, const float* __restrict__ eout_b,
    const float* __restrict__ fc_w,  const float* __restrict__ fc_b,
    const float* __restrict__ e1_w,  const float* __restrict__ e1_b,
    const float* __restrict__ e2_w,  const float* __restrict__ e2_b,
    const float* __restrict__ n1_w,  const float* __restrict__ n1_b,
    const float* __restrict__ n2_w,  const float* __restrict__ n2_b,
    const float* __restrict__ c1_w,  const float* __restrict__ c1_b,
    const float* __restrict__ c2_w,
    float* __restrict__ out)
{
    __shared__ float h[NN][PAD];
    __shared__ float xs[NN][4];
    __shared__ float pA[NN][PAD];
    __shared__ float pB[NN][PAD];
    __shared__ float part[3 * NN][PAD];  // quarters 1..3: [0:16)=agg_m, [16:19)=coord
    __shared__ __align__(16) float wb[W_TOT];
    __shared__ float hp[HH];
    __shared__ float prot[HH];

    const int b = blockIdx.x;
    const int t = threadIdx.x;

    // ---- init: x from data[:, :, :3]; h = emb_w[i] @ ein_w + ein_b ----
    if (t < NN) {
        const float* dp = data + ((size_t)b * NN + t) * (NN + 3);
        xs[t][0] = dp[0]; xs[t][1] = dp[1]; xs[t][2] = dp[2]; xs[t][3] = 0.f;

        float ev[HH];
        #pragma unroll
        for (int k = 0; k < HH; k++) ev[k] = emb_w[t * HH + k];
        float acc[HH];
        #pragma unroll
        for (int o = 0; o < HH; o++) acc[o] = ein_b[o];
        #pragma unroll
        for (int k = 0; k < HH; k++) {
            const float v = ev[k];
            #pragma unroll
            for (int o = 0; o < HH; o++) acc[o] += v * ein_w[k * HH + o];
        }
        #pragma unroll
        for (int o = 0; o < HH; o++) h[t][o] = acc[o];
    }

    for (int l = 0; l < NLAY; l++) {
        // ---- stage this layer's weights into LDS (coalesced, once) ----
        {
            const float* E1W = e1_w + l * 34 * HH;
            wb[W_E1 + t] = E1W[t];                        // t 0..511
            if (t < 32) wb[W_E1 + 512 + t] = E1W[512 + t];
            const float* N1W = n1_w + l * 2 * HH * HH;
            wb[W_N1 + t] = N1W[t];                        // t 0..511
            if (t < 256) {
                wb[W_E2 + t] = e2_w[l * HH * HH + t];
                wb[W_C1 + t] = c1_w[l * HH * HH + t];
                wb[W_N2 + t] = n2_w[l * HH * HH + t];
            }
            if (t < HH) {
                wb[W_E1B + t] = e1_b[l * HH + t];
                wb[W_E2B + t] = e2_b[l * HH + t];
                wb[W_C1B + t] = c1_b[l * HH + t];
                wb[W_C2  + t] = c2_w[l * HH + t];
                wb[W_N1B + t] = n1_b[l * HH + t];
                wb[W_N2B + t] = n2_b[l * HH + t];
            }
        }
        __syncthreads();

        // ---- Phase A: per-node e1 partials, all 512 threads.
        //      grp = t>>7: 0-> pA[0:8), 1-> pA[8:16), 2-> pB[0:8), 3-> pB[8:16)
        {
            const int node = t & (NN - 1);
            const int grp = t >> 7;
            const int ob = (grp & 1) * 8;
            float hv[HH];
            #pragma unroll
            for (int k = 0; k < HH; k++) hv[k] = h[node][k];
            if (grp < 2) {
                float acc[8];
                #pragma unroll
                for (int o = 0; o < 8; o++)
                    acc[o] = wb[W_E1B + ob + o] + wb[W_E1 + 33 * HH + ob + o];
                #pragma unroll
                for (int k = 0; k < HH; k++) {
                    const float v = hv[k];
                    #pragma unroll
                    for (int o = 0; o < 8; o++) acc[o] += v * wb[W_E1 + k * HH + ob + o];
                }
                #pragma unroll
                for (int o = 0; o < 8; o++) pA[node][ob + o] = acc[o];
            } else {
                float acc[8];
                #pragma unroll
                for (int o = 0; o < 8; o++) acc[o] = 0.f;
                #pragma unroll
                for (int k = 0; k < HH; k++) {
                    const float v = hv[k];
                    #pragma unroll
                    for (int o = 0; o < 8; o++) acc[o] += v * wb[W_E1 + (16 + k) * HH + ob + o];
                }
                #pragma unroll
                for (int o = 0; o < 8; o++) pB[node][ob + o] = acc[o];
            }
        }
        __syncthreads();

        // ---- Phase B: edges. thread t: i=t&127, quarter q4=t>>7 owns
        //      d in [q4*4+1, q4*4+4]; g in 0..1 -> d = q4*4 + g*2 + {1,2} ----
        float aggm[HH];
        float cx0 = 0.f, cx1 = 0.f, cx2 = 0.f;
        {
            const int i = t & (NN - 1);
            const int q4 = t >> 7;
            float pAi[HH];
            #pragma unroll
            for (int o = 0; o < HH; o++) pAi[o] = pA[i][o];
            const float4 xi = *(const float4*)&xs[i][0];
            #pragma unroll
            for (int o = 0; o < HH; o++) aggm[o] = 0.f;

            #pragma unroll 1
            for (int g = 0; g < 2; g++) {
                // Launder weight-base offsets: compiler must treat them as
                // loop-variant -> weight loads stay inside this iteration.
                unsigned o_col = W_E1 + 32 * HH;
                unsigned o_e2  = W_E2,  o_e2b = W_E2B;
                unsigned o_c1  = W_C1,  o_c1b = W_C1B;
                unsigned o_c2  = W_C2;
                asm volatile("" : "+v"(o_col), "+v"(o_e2), "+v"(o_e2b),
                                  "+v"(o_c1), "+v"(o_c1b), "+v"(o_c2));

                const int dbase = q4 * 4 + g * 2 + 1;
                const int j0 = (i + dbase) & (NN - 1);
                const int j1 = (i + dbase + 1) & (NN - 1);
                const float4 xj0 = *(const float4*)&xs[j0][0];
                const float4 xj1 = *(const float4*)&xs[j1][0];
                const float a00 = xi.x - xj0.x, a01 = xi.y - xj0.y, a02 = xi.z - xj0.z;
                const float a10 = xi.x - xj1.x, a11 = xi.y - xj1.y, a12 = xi.z - xj1.z;
                const float r0 = a00 * a00 + a01 * a01 + a02 * a02;
                const float r1 = a10 * a10 + a11 * a11 + a12 * a12;

                // e1 (factored) + silu
                float m0[HH], m1v[HH];
                #pragma unroll
                for (int q = 0; q < 4; q++) {
                    const float4 wc  = ((const float4*)(wb + o_col))[q];
                    const float4 p0 = *(const float4*)&pB[j0][q * 4];
                    const float4 p1 = *(const float4*)&pB[j1][q * 4];
                    m0[q*4+0]  = silu_f(pAi[q*4+0] + p0.x + r0 * wc.x);
                    m0[q*4+1]  = silu_f(pAi[q*4+1] + p0.y + r0 * wc.y);
                    m0[q*4+2]  = silu_f(pAi[q*4+2] + p0.z + r0 * wc.z);
                    m0[q*4+3]  = silu_f(pAi[q*4+3] + p0.w + r0 * wc.w);
                    m1v[q*4+0] = silu_f(pAi[q*4+0] + p1.x + r1 * wc.x);
                    m1v[q*4+1] = silu_f(pAi[q*4+1] + p1.y + r1 * wc.y);
                    m1v[q*4+2] = silu_f(pAi[q*4+2] + p1.z + r1 * wc.z);
                    m1v[q*4+3] = silu_f(pAi[q*4+3] + p1.w + r1 * wc.w);
                }

                // e2 + silu -> messages
                float ac0[HH], ac1[HH];
                #pragma unroll
                for (int q = 0; q < 4; q++) {
                    const float4 bb = ((const float4*)(wb + o_e2b))[q];
                    ac0[q*4+0] = bb.x; ac0[q*4+1] = bb.y; ac0[q*4+2] = bb.z; ac0[q*4+3] = bb.w;
                    ac1[q*4+0] = bb.x; ac1[q*4+1] = bb.y; ac1[q*4+2] = bb.z; ac1[q*4+3] = bb.w;
                }
                #pragma unroll
                for (int k = 0; k < HH; k++) {
                    const float v0 = m0[k], v1 = m1v[k];
                    #pragma unroll
                    for (int q = 0; q < 4; q++) {
                        const float4 w = ((const float4*)(wb + o_e2))[k * 4 + q];
                        ac0[q*4+0] += v0 * w.x; ac0[q*4+1] += v0 * w.y;
                        ac0[q*4+2] += v0 * w.z; ac0[q*4+3] += v0 * w.w;
                        ac1[q*4+0] += v1 * w.x; ac1[q*4+1] += v1 * w.y;
                        ac1[q*4+2] += v1 * w.z; ac1[q*4+3] += v1 * w.w;
                    }
                }
                #pragma unroll
                for (int o = 0; o < HH; o++) {
                    m0[o]  = silu_f(ac0[o]);
                    m1v[o] = silu_f(ac1[o]);
                    aggm[o] += m0[o] + m1v[o];
                }

                // coord mlp: silu(m@c1) @ c2
                #pragma unroll
                for (int q = 0; q < 4; q++) {
                    const float4 bb = ((const float4*)(wb + o_c1b))[q];
                    ac0[q*4+0] = bb.x; ac0[q*4+1] = bb.y; ac0[q*4+2] = bb.z; ac0[q*4+3] = bb.w;
                    ac1[q*4+0] = bb.x; ac1[q*4+1] = bb.y; ac1[q*4+2] = bb.z; ac1[q*4+3] = bb.w;
                }
                #pragma unroll
                for (int k = 0; k < HH; k++) {
                    const float v0 = m0[k], v1 = m1v[k];
                    #pragma unroll
                    for (int q = 0; q < 4; q++) {
                        const float4 w = ((const float4*)(wb + o_c1))[k * 4 + q];
                        ac0[q*4+0] += v0 * w.x; ac0[q*4+1] += v0 * w.y;
                        ac0[q*4+2] += v0 * w.z; ac0[q*4+3] += v0 * w.w;
                        ac1[q*4+0] += v1 * w.x; ac1[q*4+1] += v1 * w.y;
                        ac1[q*4+2] += v1 * w.z; ac1[q*4+3] += v1 * w.w;
                    }
                }
                float t0 = 0.f, t1 = 0.f;
                #pragma unroll
                for (int q = 0; q < 4; q++) {
                    const float4 cw = ((const float4*)(wb + o_c2))[q];
                    t0 += silu_f(ac0[q*4+0]) * cw.x + silu_f(ac0[q*4+1]) * cw.y
                        + silu_f(ac0[q*4+2]) * cw.z + silu_f(ac0[q*4+3]) * cw.w;
                    t1 += silu_f(ac1[q*4+0]) * cw.x + silu_f(ac1[q*4+1]) * cw.y
                        + silu_f(ac1[q*4+2]) * cw.z + silu_f(ac1[q*4+3]) * cw.w;
                }

                cx0 += a00 * t0 + a10 * t1;
                cx1 += a01 * t0 + a11 * t1;
                cx2 += a02 * t0 + a12 * t1;
            }
            // quarters 1..3 spill partials to LDS; quarter 0 keeps regs
            // (those threads run phase C themselves).
            if (t >= NN) {
                #pragma unroll
                for (int o = 0; o < HH; o++) part[t - NN][o] = aggm[o];
                float4 cxv; cxv.x = cx0; cxv.y = cx1; cxv.z = cx2; cxv.w = 0.f;
                *(float4*)&part[t - NN][16] = cxv;
            }
        }
        __syncthreads();

        // ---- Phase C: node update (t<128 == quarter 0, partials in regs) ----
        if (t < NN) {
            float am[HH];
            #pragma unroll
            for (int o = 0; o < HH; o++)
                am[o] = aggm[o] + part[t][o] + part[t + NN][o] + part[t + 2 * NN][o];
            float hv[HH];
            #pragma unroll
            for (int k = 0; k < HH; k++) hv[k] = h[t][k];

            float acc[HH];
            #pragma unroll
            for (int o = 0; o < HH; o++) acc[o] = wb[W_N1B + o];
            #pragma unroll
            for (int k = 0; k < HH; k++) {
                const float v = hv[k];
                #pragma unroll
                for (int o = 0; o < HH; o++) acc[o] += v * wb[W_N1 + k * HH + o];
            }
            #pragma unroll
            for (int k = 0; k < HH; k++) {
                const float v = am[k];
                #pragma unroll
                for (int o = 0; o < HH; o++) acc[o] += v * wb[W_N1 + (16 + k) * HH + o];
            }
            float u[HH];
            #pragma unroll
            for (int o = 0; o < HH; o++) u[o] = silu_f(acc[o]);

            float acc2[HH];
            #pragma unroll
            for (int o = 0; o < HH; o++) acc2[o] = wb[W_N2B + o];
            #pragma unroll
            for (int k = 0; k < HH; k++) {
                const float v = u[k];
                #pragma unroll
                for (int o = 0; o < HH; o++) acc2[o] += v * wb[W_N2 + k * HH + o];
            }
            #pragma unroll
            for (int o = 0; o < HH; o++) h[t][o] = hv[o] + acc2[o];

            const float inv = 1.f / 16.f;  // cnt == K exactly
            xs[t][0] += (cx0 + part[t][16] + part[t + NN][16] + part[t + 2 * NN][16]) * inv;
            xs[t][1] += (cx1 + part[t][17] + part[t + NN][17] + part[t + 2 * NN][17]) * inv;
            xs[t][2] += (cx2 + part[t][18] + part[t + NN][18] + part[t + 2 * NN][18]) * inv;
        }
        __syncthreads();
    }

    // ---- pooling (mean over nodes), then eout (linear => pool first) ----
    if (t < HH) {
        float acc = 0.f;
        for (int i = 0; i < NN; i++) acc += h[i][t];
        hp[t] = acc * (1.f / NN);
    }
    __syncthreads();
    if (t < HH) {
        float acc = eout_b[t];
        #pragma unroll
        for (int k = 0; k < HH; k++) acc += hp[k] * eout_w[k * HH + t];
        prot[t] = acc;
    }
    __syncthreads();
    // ---- fc + softmax (tiny, one lane per frame) ----
    if (t == 0) {
        float lg[NCLS];
        float mx = -1e30f;
        #pragma unroll
        for (int c = 0; c < NCLS; c++) {
            float acc = fc_b[c];
            #pragma unroll
            for (int k = 0; k < HH; k++) acc += prot[k] * fc_w[k * NCLS + c];
            lg[c] = acc;
            mx = fmaxf(mx, acc);
        }
        float s = 0.f;
        #pragma unroll
        for (int c = 0; c < NCLS; c++) { lg[c] = __expf(lg[c] - mx); s += lg[c]; }
        const float invs = 1.f / s;
        #pragma unroll
        for (int c = 0; c < NCLS; c++) out[b * NCLS + c] = lg[c] * invs;
    }
}

extern "C" void kernel_launch(void* const* d_in, const int* in_sizes, int n_in,
                              void* d_out, int out_size, void* d_ws, size_t ws_size,
                              hipStream_t stream) {
    const float* data   = (const float*)d_in[0];
    // d_in[1] = row, d_in[2] = col : fixed ring adjacency, recomputed on device
    const float* emb_w  = (const float*)d_in[3];
    const float* ein_w  = (const float*)d_in[4];
    const float* ein_b  = (const float*)d_in[5];
    const float* eout_w = (const float*)d_in[6];
    const float* eout_b = (const float*)d_in[7];
    const float* fc_w   = (const float*)d_in[8];
    const float* fc_b   = (const float*)d_in[9];
    const float* e1_w   = (const float*)d_in[10];
    const float* e1_b   = (const float*)d_in[11];
    const float* e2_w   = (const float*)d_in[12];
    const float* e2_b   = (const float*)d_in[13];
    const float* n1_w   = (const float*)d_in[14];
    const float* n1_b   = (const float*)d_in[15];
    const float* n2_w   = (const float*)d_in[16];
    const float* n2_b   = (const float*)d_in[17];
    const float* c1_w   = (const float*)d_in[18];
    const float* c1_b   = (const float*)d_in[19];
    const float* c2_w   = (const float*)d_in[20];

    GraphVampNet_73624329388105_kernel<<<NB, 512, 0, stream>>>(
        data, emb_w, ein_w, ein_b, eout_w, eout_b, fc_w, fc_b,
        e1_w, e1_b, e2_w, e2_b, n1_w, n1_b, n2_w, n2_b, c1_w, c1_b, c2_w,
        (float*)d_out);
}

// Round 2
// 333.537 us; speedup vs baseline: 1.1050x; 1.1050x over previous
//
#include <hip/hip_runtime.h>
#include <math.h>

// GraphVampNet EGNN forward. B=512, N=128, K=16, H=16, NC=6, NL=4.
// One block per frame; h/x/pA/pB in LDS across all 4 layers; fixed ring
// adjacency j=(i+d)%N d=1..16 -> pure gather, cnt==16.
// e1 factored: pA[i]=h_i@W[0:16]+b+W[33], pB[j]=h_j@W[16:32].
// R5: per-layer weights in LDS; weight-base offsets LAUNDERED via empty
// asm inside the edge-group loop so LICM/CSE cannot hoist the ~576
// loop-invariant weight loads into registers (R4: hoist -> 256 VGPR +
// 398 MB scratch spill). G=2 edge pairing: each ds_read_b128 weight row
// feeds 32 FMAs. No pointer-param helpers (R2/R3 lesson: they kill SROA).
// R6: 512 thr/block (8 waves), 4 edges/thread. launch_bounds(512,4) was
// interpreted as 4 wg/CU -> VGPR capped at 64 -> 240 MB scratch spill
// (FETCH 60MB, WRITE 174MB), dur unchanged. Lesson: the 2nd arg behaves
// like CUDA min-blocks here; 64 regs cannot hold phase B.
// R7: launch_bounds(512,2) -> 128-VGPR cap (= the 4-waves/SIMD point;
// LDS 71KB already limits to 2 blocks/CU). Phase-B live set shrunk to
// fit 128 spill-free: e2/c1 as HALF-OUTPUT passes (8 accs live, not 16;
// weight reads are wave-uniform LDS broadcasts so traffic is unchanged),
// and a single laundered zero offset (o0) replaces six laundered bases
// (weight addrs fold into ds_read offset: immediates).

#define NB   512
#define NN   128
#define HH   16
#define NCLS 6
#define NLAY 4
#define PAD  20   // LDS row stride (dwords); rows 80B -> 16B-aligned

// LDS weight-buffer float offsets (all multiples of 4 -> 16B aligned)
#define W_E1   0      // 544 = 34*16
#define W_E1B  544    // 16
#define W_E2   560    // 256
#define W_E2B  816    // 16
#define W_C1   832    // 256
#define W_C1B  1088   // 16
#define W_C2   1104   // 16
#define W_N1   1120   // 512
#define W_N1B  1632   // 16
#define W_N2   1648   // 256
#define W_N2B  1904   // 16
#define W_TOT  1920

__device__ __forceinline__ float silu_f(float v) {
    return __fdividef(v, 1.f + __expf(-v));
}

extern "C" __global__ __launch_bounds__(512, 2)
void GraphVampNet_73624329388105_kernel(
    const float* __restrict__ data,
    const float* __restrict__ emb_w,
    const float* __restrict__ ein_w, const float* __restrict__ ein_b,
    const float* __restrict__ eout_w, const float* __restrict__ eout_b,
    const float* __restrict__ fc_w,  const float* __restrict__ fc_b,
    const float* __restrict__ e1_w,  const float* __restrict__ e1_b,
    const float* __restrict__ e2_w,  const float* __restrict__ e2_b,
    const float* __restrict__ n1_w,  const float* __restrict__ n1_b,
    const float* __restrict__ n2_w,  const float* __restrict__ n2_b,
    const float* __restrict__ c1_w,  const float* __restrict__ c1_b,
    const float* __restrict__ c2_w,
    float* __restrict__ out)
{
    __shared__ float h[NN][PAD];
    __shared__ float xs[NN][4];
    __shared__ float pA[NN][PAD];
    __shared__ float pB[NN][PAD];
    __shared__ float part[3 * NN][PAD];  // quarters 1..3: [0:16)=agg_m, [16:19)=coord
    __shared__ __align__(16) float wb[W_TOT];
    __shared__ float hp[HH];
    __shared__ float prot[HH];

    const int b = blockIdx.x;
    const int t = threadIdx.x;

    // ---- init: x from data[:, :, :3]; h = emb_w[i] @ ein_w + ein_b ----
    if (t < NN) {
        const float* dp = data + ((size_t)b * NN + t) * (NN + 3);
        xs[t][0] = dp[0]; xs[t][1] = dp[1]; xs[t][2] = dp[2]; xs[t][3] = 0.f;

        float ev[HH];
        #pragma unroll
        for (int k = 0; k < HH; k++) ev[k] = emb_w[t * HH + k];
        float acc[HH];
        #pragma unroll
        for (int o = 0; o < HH; o++) acc[o] = ein_b[o];
        #pragma unroll
        for (int k = 0; k < HH; k++) {
            const float v = ev[k];
            #pragma unroll
            for (int o = 0; o < HH; o++) acc[o] += v * ein_w[k * HH + o];
        }
        #pragma unroll
        for (int o = 0; o < HH; o++) h[t][o] = acc[o];
    }

    for (int l = 0; l < NLAY; l++) {
        // ---- stage this layer's weights into LDS (coalesced, once) ----
        {
            const float* E1W = e1_w + l * 34 * HH;
            wb[W_E1 + t] = E1W[t];                        // t 0..511
            if (t < 32) wb[W_E1 + 512 + t] = E1W[512 + t];
            const float* N1W = n1_w + l * 2 * HH * HH;
            wb[W_N1 + t] = N1W[t];                        // t 0..511
            if (t < 256) {
                wb[W_E2 + t] = e2_w[l * HH * HH + t];
                wb[W_C1 + t] = c1_w[l * HH * HH + t];
                wb[W_N2 + t] = n2_w[l * HH * HH + t];
            }
            if (t < HH) {
                wb[W_E1B + t] = e1_b[l * HH + t];
                wb[W_E2B + t] = e2_b[l * HH + t];
                wb[W_C1B + t] = c1_b[l * HH + t];
                wb[W_C2  + t] = c2_w[l * HH + t];
                wb[W_N1B + t] = n1_b[l * HH + t];
                wb[W_N2B + t] = n2_b[l * HH + t];
            }
        }
        __syncthreads();

        // ---- Phase A: per-node e1 partials, all 512 threads.
        //      grp = t>>7: 0-> pA[0:8), 1-> pA[8:16), 2-> pB[0:8), 3-> pB[8:16)
        {
            const int node = t & (NN - 1);
            const int grp = t >> 7;
            const int ob = (grp & 1) * 8;
            float hv[HH];
            #pragma unroll
            for (int k = 0; k < HH; k++) hv[k] = h[node][k];
            if (grp < 2) {
                float acc[8];
                #pragma unroll
                for (int o = 0; o < 8; o++)
                    acc[o] = wb[W_E1B + ob + o] + wb[W_E1 + 33 * HH + ob + o];
                #pragma unroll
                for (int k = 0; k < HH; k++) {
                    const float v = hv[k];
                    #pragma unroll
                    for (int o = 0; o < 8; o++) acc[o] += v * wb[W_E1 + k * HH + ob + o];
                }
                #pragma unroll
                for (int o = 0; o < 8; o++) pA[node][ob + o] = acc[o];
            } else {
                float acc[8];
                #pragma unroll
                for (int o = 0; o < 8; o++) acc[o] = 0.f;
                #pragma unroll
                for (int k = 0; k < HH; k++) {
                    const float v = hv[k];
                    #pragma unroll
                    for (int o = 0; o < 8; o++) acc[o] += v * wb[W_E1 + (16 + k) * HH + ob + o];
                }
                #pragma unroll
                for (int o = 0; o < 8; o++) pB[node][ob + o] = acc[o];
            }
        }
        __syncthreads();

        // ---- Phase B: edges. thread t: i=t&127, quarter q4=t>>7 owns
        //      d in [q4*4+1, q4*4+4]; g in 0..1 -> d = q4*4 + g*2 + {1,2} ----
        float aggm[HH];
        float cx0 = 0.f, cx1 = 0.f, cx2 = 0.f;
        {
            const int i = t & (NN - 1);
            const int q4 = t >> 7;
            float pAi[HH];
            #pragma unroll
            for (int o = 0; o < HH; o++) pAi[o] = pA[i][o];
            const float4 xi = *(const float4*)&xs[i][0];
            #pragma unroll
            for (int o = 0; o < HH; o++) aggm[o] = 0.f;

            #pragma unroll 1
            for (int g = 0; g < 2; g++) {
                // Launder ONE zero offset: every weight address becomes
                // (wbl + const) -> loop-variant (no LICM hoist of the ~576
                // weight loads), single VGPR, consts fold into ds_read
                // offset: immediates.
                unsigned o0 = 0;
                asm volatile("" : "+v"(o0));
                const float* wbl = (const float*)wb + o0;

                const int dbase = q4 * 4 + g * 2 + 1;
                const int j0 = (i + dbase) & (NN - 1);
                const int j1 = (i + dbase + 1) & (NN - 1);
                const float4 xj0 = *(const float4*)&xs[j0][0];
                const float4 xj1 = *(const float4*)&xs[j1][0];
                const float a00 = xi.x - xj0.x, a01 = xi.y - xj0.y, a02 = xi.z - xj0.z;
                const float a10 = xi.x - xj1.x, a11 = xi.y - xj1.y, a12 = xi.z - xj1.z;
                const float r0 = a00 * a00 + a01 * a01 + a02 * a02;
                const float r1 = a10 * a10 + a11 * a11 + a12 * a12;

                // e1 (factored) + silu
                float m0[HH], m1v[HH];
                #pragma unroll
                for (int q = 0; q < 4; q++) {
                    const float4 wc  = ((const float4*)(wbl + W_E1 + 32 * HH))[q];
                    const float4 p0 = *(const float4*)&pB[j0][q * 4];
                    const float4 p1 = *(const float4*)&pB[j1][q * 4];
                    m0[q*4+0]  = silu_f(pAi[q*4+0] + p0.x + r0 * wc.x);
                    m0[q*4+1]  = silu_f(pAi[q*4+1] + p0.y + r0 * wc.y);
                    m0[q*4+2]  = silu_f(pAi[q*4+2] + p0.z + r0 * wc.z);
                    m0[q*4+3]  = silu_f(pAi[q*4+3] + p0.w + r0 * wc.w);
                    m1v[q*4+0] = silu_f(pAi[q*4+0] + p1.x + r1 * wc.x);
                    m1v[q*4+1] = silu_f(pAi[q*4+1] + p1.y + r1 * wc.y);
                    m1v[q*4+2] = silu_f(pAi[q*4+2] + p1.z + r1 * wc.z);
                    m1v[q*4+3] = silu_f(pAi[q*4+3] + p1.w + r1 * wc.w);
                }

                // e2 + silu -> mp0/mp1, HALF-OUTPUT passes (8 accs live)
                float mp0[HH], mp1[HH];
                #pragma unroll
                for (int hf = 0; hf < 2; hf++) {
                    float ac0[8], ac1[8];
                    #pragma unroll
                    for (int q = 0; q < 2; q++) {
                        const float4 bb = ((const float4*)(wbl + W_E2B))[hf * 2 + q];
                        ac0[q*4+0] = bb.x; ac0[q*4+1] = bb.y; ac0[q*4+2] = bb.z; ac0[q*4+3] = bb.w;
                        ac1[q*4+0] = bb.x; ac1[q*4+1] = bb.y; ac1[q*4+2] = bb.z; ac1[q*4+3] = bb.w;
                    }
                    #pragma unroll
                    for (int k = 0; k < HH; k++) {
                        const float v0 = m0[k], v1 = m1v[k];
                        #pragma unroll
                        for (int q = 0; q < 2; q++) {
                            const float4 w = ((const float4*)(wbl + W_E2))[k * 4 + hf * 2 + q];
                            ac0[q*4+0] += v0 * w.x; ac0[q*4+1] += v0 * w.y;
                            ac0[q*4+2] += v0 * w.z; ac0[q*4+3] += v0 * w.w;
                            ac1[q*4+0] += v1 * w.x; ac1[q*4+1] += v1 * w.y;
                            ac1[q*4+2] += v1 * w.z; ac1[q*4+3] += v1 * w.w;
                        }
                    }
                    #pragma unroll
                    for (int o = 0; o < 8; o++) {
                        const float s0 = silu_f(ac0[o]);
                        const float s1 = silu_f(ac1[o]);
                        mp0[hf * 8 + o] = s0;
                        mp1[hf * 8 + o] = s1;
                        aggm[hf * 8 + o] += s0 + s1;
                    }
                }

                // coord mlp: silu(mp@c1) @ c2, HALF-OUTPUT passes
                float t0 = 0.f, t1 = 0.f;
                #pragma unroll
                for (int hf = 0; hf < 2; hf++) {
                    float ac0[8], ac1[8];
                    #pragma unroll
                    for (int q = 0; q < 2; q++) {
                        const float4 bb = ((const float4*)(wbl + W_C1B))[hf * 2 + q];
                        ac0[q*4+0] = bb.x; ac0[q*4+1] = bb.y; ac0[q*4+2] = bb.z; ac0[q*4+3] = bb.w;
                        ac1[q*4+0] = bb.x; ac1[q*4+1] = bb.y; ac1[q*4+2] = bb.z; ac1[q*4+3] = bb.w;
                    }
                    #pragma unroll
                    for (int k = 0; k < HH; k++) {
                        const float v0 = mp0[k], v1 = mp1[k];
                        #pragma unroll
                        for (int q = 0; q < 2; q++) {
                            const float4 w = ((const float4*)(wbl + W_C1))[k * 4 + hf * 2 + q];
                            ac0[q*4+0] += v0 * w.x; ac0[q*4+1] += v0 * w.y;
                            ac0[q*4+2] += v0 * w.z; ac0[q*4+3] += v0 * w.w;
                            ac1[q*4+0] += v1 * w.x; ac1[q*4+1] += v1 * w.y;
                            ac1[q*4+2] += v1 * w.z; ac1[q*4+3] += v1 * w.w;
                        }
                    }
                    #pragma unroll
                    for (int q = 0; q < 2; q++) {
                        const float4 cw = ((const float4*)(wbl + W_C2))[hf * 2 + q];
                        t0 += silu_f(ac0[q*4+0]) * cw.x + silu_f(ac0[q*4+1]) * cw.y
                            + silu_f(ac0[q*4+2]) * cw.z + silu_f(ac0[q*4+3]) * cw.w;
                        t1 += silu_f(ac1[q*4+0]) * cw.x + silu_f(ac1[q*4+1]) * cw.y
                            + silu_f(ac1[q*4+2]) * cw.z + silu_f(ac1[q*4+3]) * cw.w;
                    }
                }

                cx0 += a00 * t0 + a10 * t1;
                cx1 += a01 * t0 + a11 * t1;
                cx2 += a02 * t0 + a12 * t1;
            }
            // quarters 1..3 spill partials to LDS; quarter 0 keeps regs
            // (those threads run phase C themselves).
            if (t >= NN) {
                #pragma unroll
                for (int o = 0; o < HH; o++) part[t - NN][o] = aggm[o];
                float4 cxv; cxv.x = cx0; cxv.y = cx1; cxv.z = cx2; cxv.w = 0.f;
                *(float4*)&part[t - NN][16] = cxv;
            }
        }
        __syncthreads();

        // ---- Phase C: node update (t<128 == quarter 0, partials in regs) ----
        if (t < NN) {
            float am[HH];
            #pragma unroll
            for (int o = 0; o < HH; o++)
                am[o] = aggm[o] + part[t][o] + part[t + NN][o] + part[t + 2 * NN][o];
            float hv[HH];
            #pragma unroll
            for (int k = 0; k < HH; k++) hv[k] = h[t][k];

            float acc[HH];
            #pragma unroll
            for (int o = 0; o < HH; o++) acc[o] = wb[W_N1B + o];
            #pragma unroll
            for (int k = 0; k < HH; k++) {
                const float v = hv[k];
                #pragma unroll
                for (int o = 0; o < HH; o++) acc[o] += v * wb[W_N1 + k * HH + o];
            }
            #pragma unroll
            for (int k = 0; k < HH; k++) {
                const float v = am[k];
                #pragma unroll
                for (int o = 0; o < HH; o++) acc[o] += v * wb[W_N1 + (16 + k) * HH + o];
            }
            float u[HH];
            #pragma unroll
            for (int o = 0; o < HH; o++) u[o] = silu_f(acc[o]);

            float acc2[HH];
            #pragma unroll
            for (int o = 0; o < HH; o++) acc2[o] = wb[W_N2B + o];
            #pragma unroll
            for (int k = 0; k < HH; k++) {
                const float v = u[k];
                #pragma unroll
                for (int o = 0; o < HH; o++) acc2[o] += v * wb[W_N2 + k * HH + o];
            }
            #pragma unroll
            for (int o = 0; o < HH; o++) h[t][o] = hv[o] + acc2[o];

            const float inv = 1.f / 16.f;  // cnt == K exactly
            xs[t][0] += (cx0 + part[t][16] + part[t + NN][16] + part[t + 2 * NN][16]) * inv;
            xs[t][1] += (cx1 + part[t][17] + part[t + NN][17] + part[t + 2 * NN][17]) * inv;
            xs[t][2] += (cx2 + part[t][18] + part[t + NN][18] + part[t + 2 * NN][18]) * inv;
        }
        __syncthreads();
    }

    // ---- pooling (mean over nodes), then eout (linear => pool first) ----
    if (t < HH) {
        float acc = 0.f;
        for (int i = 0; i < NN; i++) acc += h[i][t];
        hp[t] = acc * (1.f / NN);
    }
    __syncthreads();
    if (t < HH) {
        float acc = eout_b[t];
        #pragma unroll
        for (int k = 0; k < HH; k++) acc += hp[k] * eout_w[k * HH + t];
        prot[t] = acc;
    }
    __syncthreads();
    // ---- fc + softmax (tiny, one lane per frame) ----
    if (t == 0) {
        float lg[NCLS];
        float mx = -1e30f;
        #pragma unroll
        for (int c = 0; c < NCLS; c++) {
            float acc = fc_b[c];
            #pragma unroll
            for (int k = 0; k < HH; k++) acc += prot[k] * fc_w[k * NCLS + c];
            lg[c] = acc;
            mx = fmaxf(mx, acc);
        }
        float s = 0.f;
        #pragma unroll
        for (int c = 0; c < NCLS; c++) { lg[c] = __expf(lg[c] - mx); s += lg[c]; }
        const float invs = 1.f / s;
        #pragma unroll
        for (int c = 0; c < NCLS; c++) out[b * NCLS + c] = lg[c] * invs;
    }
}

extern "C" void kernel_launch(void* const* d_in, const int* in_sizes, int n_in,
                              void* d_out, int out_size, void* d_ws, size_t ws_size,
                              hipStream_t stream) {
    const float* data   = (const float*)d_in[0];
    // d_in[1] = row, d_in[2] = col : fixed ring adjacency, recomputed on device
    const float* emb_w  = (const float*)d_in[3];
    const float* ein_w  = (const float*)d_in[4];
    const float* ein_b  = (const float*)d_in[5];
    const float* eout_w = (const float*)d_in[6];
    const float* eout_b = (const float*)d_in[7];
    const float* fc_w   = (const float*)d_in[8];
    const float* fc_b   = (const float*)d_in[9];
    const float* e1_w   = (const float*)d_in[10];
    const float* e1_b   = (const float*)d_in[11];
    const float* e2_w   = (const float*)d_in[12];
    const float* e2_b   = (const float*)d_in[13];
    const float* n1_w   = (const float*)d_in[14];
    const float* n1_b   = (const float*)d_in[15];
    const float* n2_w   = (const float*)d_in[16];
    const float* n2_b   = (const float*)d_in[17];
    const float* c1_w   = (const float*)d_in[18];
    const float* c1_b   = (const float*)d_in[19];
    const float* c2_w   = (const float*)d_in[20];

    GraphVampNet_73624329388105_kernel<<<NB, 512, 0, stream>>>(
        data, emb_w, ein_w, ein_b, eout_w, eout_b, fc_w, fc_b,
        e1_w, e1_b, e2_w, e2_b, n1_w, n1_b, n2_w, n2_b, c1_w, c1_b, c2_w,
        (float*)d_out);
}